// Round 2
// baseline (526.987 us; speedup 1.0000x reference)
//
#include <hip/hip_runtime.h>
#include <hip/hip_bf16.h>

typedef unsigned int u32;
typedef unsigned long long u64;

// ---------------- Threefry-2x32 (20 rounds), exact JAX semantics ----------------
__host__ __device__ __forceinline__ void tf2x32(u32 k0, u32 k1, u32 x0, u32 x1,
                                                u32& o0, u32& o1)
{
    const u32 ks2 = k0 ^ k1 ^ 0x1BD11BDAu;
    x0 += k0; x1 += k1;
#define TF_R(r) { x0 += x1; x1 = (x1 << (r)) | (x1 >> (32 - (r))); x1 ^= x0; }
    TF_R(13) TF_R(15) TF_R(26) TF_R(6)
    x0 += k1; x1 += ks2 + 1u;
    TF_R(17) TF_R(29) TF_R(16) TF_R(24)
    x0 += ks2; x1 += k0 + 2u;
    TF_R(13) TF_R(15) TF_R(26) TF_R(6)
    x0 += k0; x1 += k1 + 3u;
    TF_R(17) TF_R(29) TF_R(16) TF_R(24)
    x0 += k1; x1 += ks2 + 4u;
    TF_R(13) TF_R(15) TF_R(26) TF_R(6)
    x0 += ks2; x1 += k0 + 5u;
#undef TF_R
    o0 = x0; o1 = x1;
}

// partitionable random_bits for 32-bit: counter = (hi=0, lo=e), bits = o0 ^ o1
__device__ __forceinline__ u32 rbits(u32 k0, u32 k1, u32 e)
{
    u32 o0, o1; tf2x32(k0, k1, 0u, e, o0, o1); return o0 ^ o1;
}

#define HW        262144u      // 512*512 = 2^18
#define PMASK     262143u
#define KEEP      183500u      // int(262144*0.7)
#define NX        50331648u    // 64*3*512*512
#define NM        16777216u    // 64*512*512
#define LO_F      (-0.99999994039535522461f)   // -(1-2^-24)

__device__ __forceinline__ float noise_from_bits(u32 bits)
{
    float f  = __uint_as_float((bits >> 9) | 0x3F800000u) - 1.0f;   // [0,1)
    float un = fmaf(f, 2.0f, LO_F);
    un = fmaxf(LO_F, un);
    // Giles single-precision erfinv (XLA-style)
    float w = -__logf(fmaf(-un, un, 1.0f));
    float p;
    if (w < 5.0f) {
        w -= 2.5f;
        p = 2.81022636e-08f;
        p = fmaf(p, w, 3.43273939e-07f);
        p = fmaf(p, w, -3.5233877e-06f);
        p = fmaf(p, w, -4.39150654e-06f);
        p = fmaf(p, w, 0.00021858087f);
        p = fmaf(p, w, -0.00125372503f);
        p = fmaf(p, w, -0.00417768164f);
        p = fmaf(p, w, 0.246640727f);
        p = fmaf(p, w, 1.50140941f);
    } else {
        w = __fsqrt_rn(w) - 3.0f;
        p = -0.000200214257f;
        p = fmaf(p, w, 0.000100950558f);
        p = fmaf(p, w, 0.00134934322f);
        p = fmaf(p, w, -0.00367342844f);
        p = fmaf(p, w, 0.00573950773f);
        p = fmaf(p, w, -0.0076224613f);
        p = fmaf(p, w, 0.00943887047f);
        p = fmaf(p, w, 1.00167406f);
        p = fmaf(p, w, 2.83297682f);
    }
    float ei = p * un;
    return fmaf(1.41421356f * ei, 0.1f, 1.0f);
}

// K1: generate m = bits>>9 for all 16.7M pixels into the mask output region.
__global__ __launch_bounds__(256) void k1_gen(u32 mk0, u32 mk1, uint4* mv)
{
    u32 tid = blockIdx.x * 256u + threadIdx.x;    // 4194304 uint4 units
    u32 e = tid << 2;
    uint4 q;
    q.x = rbits(mk0, mk1, e)      >> 9;
    q.y = rbits(mk0, mk1, e + 1u) >> 9;
    q.z = rbits(mk0, mk1, e + 2u) >> 9;
    q.w = rbits(mk0, mk1, e + 3u) >> 9;
    mv[tid] = q;
}

// K2: one block per sample row. Exact KEEP-th smallest (m, p) key via:
//   pass1: coarse hist (m>>11, 4096 bins in LDS) -> bin B, rank r within B
//   pass2: collect candidates with coarse==B as packed ((m&2047)<<18)|p keys,
//          parallel exact rank-select of the r-th smallest.
__global__ __launch_bounds__(1024) void k2_select(const u32* mbuf, u64* rowsel)
{
    __shared__ u32 hist[4096];
    __shared__ u32 sh[1026];
    __shared__ u32 cand[512];
    __shared__ u32 ccnt;
    const int t = threadIdx.x;          // 1024
    const u32 row = blockIdx.x;         // 64
    const uint4* mv = (const uint4*)mbuf + ((u64)row << 16);

    for (int i = t; i < 4096; i += 1024) hist[i] = 0;
    if (t == 0) ccnt = 0;
    __syncthreads();

    // pass 1: coarse histogram
#pragma unroll 1
    for (int i = 0; i < 64; ++i) {
        uint4 q = mv[(i << 10) + t];
        atomicAdd(&hist[q.x >> 11], 1u);
        atomicAdd(&hist[q.y >> 11], 1u);
        atomicAdd(&hist[q.z >> 11], 1u);
        atomicAdd(&hist[q.w >> 11], 1u);
    }
    __syncthreads();

    // rank: smallest bin B with cumulative >= KEEP  (4 bins per thread)
    u32 v0 = hist[t * 4], v1 = hist[t * 4 + 1], v2 = hist[t * 4 + 2], v3 = hist[t * 4 + 3];
    sh[t] = v0 + v1 + v2 + v3;
    __syncthreads();
    if (t == 0) {
        u32 run = 0, c = 0;
        for (; c < 1023u; ++c) { u32 cs = sh[c]; if (run + cs >= KEEP) break; run += cs; }
        sh[1024] = c; sh[1025] = run;
    }
    __syncthreads();
    u32 c = sh[1024];
    if (t == (int)c) {
        u32 run = sh[1025];
        u32 v[4] = { v0, v1, v2, v3 };
        u32 b = (u32)t * 4u + 3u, r = KEEP - run;
#pragma unroll
        for (int i = 0; i < 4; ++i) {
            if (run + v[i] >= KEEP) { b = (u32)t * 4u + (u32)i; r = KEEP - run; break; }
            run += v[i];
        }
        sh[1024] = b; sh[1025] = r;
    }
    __syncthreads();
    const u32 B = sh[1024];
    const u32 r = sh[1025];
    __syncthreads();

    // pass 2: collect candidates in coarse bin B
#pragma unroll 1
    for (int i = 0; i < 64; ++i) {
        u32 vi = (u32)(i << 10) + (u32)t;
        uint4 q = mv[vi];
        u32 p = vi << 2;
        if ((q.x >> 11) == B) { u32 pos = atomicAdd(&ccnt, 1u); if (pos < 512u) cand[pos] = ((q.x & 2047u) << 18) | p; }
        if ((q.y >> 11) == B) { u32 pos = atomicAdd(&ccnt, 1u); if (pos < 512u) cand[pos] = ((q.y & 2047u) << 18) | (p + 1u); }
        if ((q.z >> 11) == B) { u32 pos = atomicAdd(&ccnt, 1u); if (pos < 512u) cand[pos] = ((q.z & 2047u) << 18) | (p + 2u); }
        if ((q.w >> 11) == B) { u32 pos = atomicAdd(&ccnt, 1u); if (pos < 512u) cand[pos] = ((q.w & 2047u) << 18) | (p + 3u); }
    }
    __syncthreads();

    // exact select: element with 0-based rank r-1 among unique keys
    u32 cnt = ccnt; if (cnt > 512u) cnt = 512u;
    if ((u32)t < cnt) {
        u32 me = cand[t];
        u32 rk = 0;
        for (u32 j = 0; j < cnt; ++j) rk += (cand[j] < me) ? 1u : 0u;
        if (rk == r - 1u) {
            u32 mstar = (B << 11) | (me >> 18);
            rowsel[row] = ((u64)mstar << 18) | (u64)(me & 0x3FFFFu);
        }
    }
}

// K3: fused mask + noise + multiply. One thread owns pixel-quad (b, p..p+3)
// for all 3 channels; converts m -> mask float in place (same thread, same
// address: read-then-write, no race) and writes the 3 output channel quads.
__global__ __launch_bounds__(256) void k3_fused(const float4* x4, u32* mmask,
                                                const u64* rowsel, float4* out4,
                                                u32 nk0, u32 nk1)
{
    u32 tid = blockIdx.x * 256u + threadIdx.x;    // 4194304 pixel-quads
    u32 b  = tid >> 16;                           // sample
    u32 pq = tid & 65535u;                        // pixel-quad within sample
    u32 p  = pq << 2;
    u64 kst = rowsel[b];
    uint4 q = ((const uint4*)mmask)[tid];
    float4 mk;
    mk.x = ((((u64)q.x << 18) | (u64)p)        <= kst) ? 1.0f : 0.0f;
    mk.y = ((((u64)q.y << 18) | (u64)(p + 1u)) <= kst) ? 1.0f : 0.0f;
    mk.z = ((((u64)q.z << 18) | (u64)(p + 2u)) <= kst) ? 1.0f : 0.0f;
    mk.w = ((((u64)q.w << 18) | (u64)(p + 3u)) <= kst) ? 1.0f : 0.0f;
#pragma unroll
    for (u32 ch = 0; ch < 3u; ++ch) {
        u32 xi = ((b * 3u + ch) << 16) + pq;
        u32 e  = ((b * 3u + ch) << 18) + p;
        float4 xv = x4[xi];
        float4 rr;
        rr.x = (xv.x * mk.x) * noise_from_bits(rbits(nk0, nk1, e));
        rr.y = (xv.y * mk.y) * noise_from_bits(rbits(nk0, nk1, e + 1u));
        rr.z = (xv.z * mk.z) * noise_from_bits(rbits(nk0, nk1, e + 2u));
        rr.w = (xv.w * mk.w) * noise_from_bits(rbits(nk0, nk1, e + 3u));
        out4[xi] = rr;
    }
    ((float4*)mmask)[tid] = mk;                   // mask output (in place over m)
}

extern "C" void kernel_launch(void* const* d_in, const int* in_sizes, int n_in,
                              void* d_out, int out_size, void* d_ws, size_t ws_size,
                              hipStream_t stream) {
    const float* x = (const float*)d_in[0];
    float* xout = (float*)d_out;                  // 50331648 floats (x output)
    u32*  mmask = (u32*)(xout + NX);              // mask region: m then mask floats
    u64*  rowsel = (u64*)d_ws;                    // 64 x u64 = 512 B scratch

    u32 mk0, mk1, nk0, nk1;
    tf2x32(0u, 42u, 0u, 0u, mk0, mk1);            // k_mask = threefry(key=42, ctr=(0,0))
    tf2x32(0u, 42u, 0u, 1u, nk0, nk1);            // k_noise = threefry(key=42, ctr=(0,1))

    k1_gen<<<16384, 256, 0, stream>>>(mk0, mk1, (uint4*)mmask);
    k2_select<<<64, 1024, 0, stream>>>(mmask, rowsel);
    k3_fused<<<16384, 256, 0, stream>>>((const float4*)x, mmask, rowsel,
                                        (float4*)xout, nk0, nk1);
    (void)d_ws; (void)ws_size; (void)in_sizes; (void)n_in; (void)out_size;
}